// Round 5
// baseline (163.868 us; speedup 1.0000x reference)
//
#include <hip/hip_runtime.h>
#include <math.h>

// Problem shape (fixed by setup_inputs)
#define BATCH 32
#define HH 768
#define WW 768
#define NBLK 2048   // 32 batches x 8 region-rows x 8 row-chunks

typedef float v4f __attribute__((ext_vector_type(4)));

// ---------------------------------------------------------------------------
// Kernel 1: block = (b, ri, chunk) covering 12 full-width rows (36 KB span).
// SPLIT CACHE POLICY:
//   pred -> non-temporal loads (bypass MALL allocation, stream from HBM)
//   gt   -> regular loads (served from MALL: it is the last-written input at
//           reset time, hence resident -- rounds 0-2 showed FETCH == exactly
//           one array).
// Theory: MALL hit-service and HBM nt-miss are partially parallel paths
// (2.69 TB/s regular-both vs 3.43 TB/s nt-both); routing each array to its
// natural path lets them overlap -> up to ~6 TB/s aggregate.
// ---------------------------------------------------------------------------
__global__ __launch_bounds__(256) void region_reduce(
    const float* __restrict__ pred, const float* __restrict__ gt,
    float* __restrict__ sq_out, float* __restrict__ dws)
{
    const int bid   = blockIdx.x;        // b*64 + ri*8 + chunk
    const int b     = bid >> 6;
    const int ri    = (bid >> 3) & 7;
    const int chunk = bid & 7;
    const size_t base = (size_t)b * (HH * WW) + (size_t)(ri * 96 + chunk * 12) * WW;

    const int t = threadIdx.x;
    const int w = t >> 6;       // wave 0..3
    const int l = t & 63;

    // float4 element for (w, slot k, lane l): m = (w*9+k)*64 + l   (m in [0,2304))
    const v4f* pp = (const v4f*)(pred + base) + (w * 9) * 64 + l;
    const v4f* gp = (const v4f*)(gt   + base) + (w * 9) * 64 + l;

    v4f p[9], q4[9];
    #pragma unroll
    for (int k = 0; k < 9; ++k) p[k]  = __builtin_nontemporal_load(pp + k * 64);
    #pragma unroll
    for (int k = 0; k < 9; ++k) q4[k] = gp[k * 64];     // regular (MALL-served)

    // consume: element m = (w*9+k)*64+l -> col4 c = 64*(k%3)+l -> rj = c/24.
    float sq = 0.f, ds0 = 0.f, ds1 = 0.f, ds2 = 0.f;
    #pragma unroll
    for (int k = 0; k < 9; ++k) {
        const float dx = p[k][0] - q4[k][0];
        const float dy = p[k][1] - q4[k][1];
        const float dz = p[k][2] - q4[k][2];
        const float dw = p[k][3] - q4[k][3];
        sq += (dx * dx + dy * dy) + (dz * dz + dw * dw);
        const float s = (dx + dy) + (dz + dw);
        if (k % 3 == 0)      ds0 += s;   // folds at compile time
        else if (k % 3 == 1) ds1 += s;
        else                 ds2 += s;
    }

    // regional bins: bucket i covers col4 c = 64*i + l  ->  rj = (64*i+l)/24
    __shared__ float bins[8];
    __shared__ float lsq[4];
    if (t < 8) bins[t] = 0.f;
    __syncthreads();
    atomicAdd(&bins[l / 24],         ds0);
    atomicAdd(&bins[(64 + l) / 24],  ds1);
    atomicAdd(&bins[(128 + l) / 24], ds2);

    // sq: reduce across the full 64-lane wave
    #pragma unroll
    for (int off_ = 32; off_ > 0; off_ >>= 1) sq += __shfl_down(sq, off_, 64);
    if (l == 0) lsq[w] = sq;
    __syncthreads();

    if (t < 8)
        dws[((((b << 3) + ri) << 3) + t) * 8 + chunk] = bins[t];
    if (t == 0) sq_out[bid] = (lsq[0] + lsq[1]) + (lsq[2] + lsq[3]);
}

// ---------------------------------------------------------------------------
// Kernel 2: single block. Aggregates chunk partials -> level-3 regions,
// builds levels 2/1, count loss, domain CE, final weighted sum.
// ---------------------------------------------------------------------------
__global__ __launch_bounds__(256) void finalize(
    const float* __restrict__ sq, const float* __restrict__ dws,
    const float* __restrict__ rgb, const float* __restrict__ th,
    float* __restrict__ out)
{
    __shared__ float d[NBLK];        // level-3 region diffs (b*64 + ri*8 + rj)
    __shared__ float d2[BATCH * 16];
    __shared__ float d1[BATCH * 4];
    __shared__ float redbuf[4 * 6];
    const int t = threadIdx.x;

    // density partials (2048 floats as 512 float4)
    float s_sq = 0.f;
    const float4* sq4 = (const float4*)sq;
    #pragma unroll
    for (int k = 0; k < 2; ++k) {
        const float4 v = sq4[t + 256 * k];
        s_sq += (v.x + v.y) + (v.z + v.w);
    }

    // level-3 region diffs: sum 8 chunk partials each
    float l3 = 0.f;
    #pragma unroll
    for (int k = 0; k < 8; ++k) {
        const int r = t + 256 * k;
        const float4* dp = (const float4*)(dws + r * 8);
        const float4 a = dp[0], bb = dp[1];
        const float v = ((a.x + a.y) + (a.z + a.w)) + ((bb.x + bb.y) + (bb.z + bb.w));
        d[r] = v;
        l3 += fabsf(v);
    }
    __syncthreads();

    // level 2: 32 batches x 16 cells, 2x2 aggregation of level-3
    float l2 = 0.f;
    #pragma unroll
    for (int k = 0; k < 2; ++k) {
        const int i = t + 256 * k;
        const int b = i >> 4, r2 = i & 15;
        const int i2 = r2 >> 2, j2 = r2 & 3;
        const float* db = d + b * 64;
        const float v = (db[(2 * i2) * 8 + 2 * j2]     + db[(2 * i2) * 8 + 2 * j2 + 1])
                      + (db[(2 * i2 + 1) * 8 + 2 * j2] + db[(2 * i2 + 1) * 8 + 2 * j2 + 1]);
        d2[i] = v;
        l2 += fabsf(v);
    }
    __syncthreads();

    // level 1: 32 x 4 cells
    float l1 = 0.f;
    if (t < BATCH * 4) {
        const int b = t >> 2, r1 = t & 3;
        const int i1 = r1 >> 1, j1 = r1 & 1;
        const float* db = d2 + b * 16;
        const float v = (db[(2 * i1) * 4 + 2 * j1]     + db[(2 * i1) * 4 + 2 * j1 + 1])
                      + (db[(2 * i1 + 1) * 4 + 2 * j1] + db[(2 * i1 + 1) * 4 + 2 * j1 + 1]);
        d1[t] = v;
        l1 = fabsf(v);
    }
    __syncthreads();

    // per-batch count diff + domain CE
    float cnt = 0.f, dom = 0.f;
    if (t < BATCH) {
        const float c = (d1[t * 4] + d1[t * 4 + 1]) + (d1[t * 4 + 2] + d1[t * 4 + 3]);
        cnt = fabsf(c);
        const float x0 = rgb[t * 2], x1 = rgb[t * 2 + 1];
        const float mx = fmaxf(x0, x1);
        dom  = (mx + logf(expf(x0 - mx) + expf(x1 - mx))) - x0;
        const float y0 = th[t * 2], y1 = th[t * 2 + 1];
        const float my = fmaxf(y0, y1);
        dom += (my + logf(expf(y0 - my) + expf(y1 - my))) - y1;
    }

    // fused 6-value reduction: wave shuffle, then 4-wave LDS combine
    float vals[6] = {s_sq, l3, l2, l1, cnt, dom};
    #pragma unroll
    for (int off = 32; off > 0; off >>= 1) {
        #pragma unroll
        for (int j = 0; j < 6; ++j) vals[j] += __shfl_down(vals[j], off, 64);
    }
    const int wave = t >> 6;
    if ((t & 63) == 0) {
        #pragma unroll
        for (int j = 0; j < 6; ++j) redbuf[wave * 6 + j] = vals[j];
    }
    __syncthreads();
    if (t == 0) {
        float S[6];
        #pragma unroll
        for (int j = 0; j < 6; ++j)
            S[j] = (redbuf[j] + redbuf[6 + j]) + (redbuf[12 + j] + redbuf[18 + j]);
        const float density  = S[0] / (float)((size_t)BATCH * HH * WW);
        const float count_l  = S[4] / (float)BATCH;
        const float regional = ((S[3] + S[2] + S[1]) / (float)BATCH) / 192.0f;
        const float domain   = S[5] / 64.0f;
        out[0] = 100.0f * density + 0.001f * count_l + 1.0f * regional + 0.5f * domain;
    }
}

extern "C" void kernel_launch(void* const* d_in, const int* in_sizes, int n_in,
                              void* d_out, int out_size, void* d_ws, size_t ws_size,
                              hipStream_t stream) {
    const float* pred = (const float*)d_in[0];
    const float* gt   = (const float*)d_in[1];
    const float* rgb  = (const float*)d_in[2];
    const float* th   = (const float*)d_in[3];
    float* out = (float*)d_out;

    float* sq  = (float*)d_ws;         // [2048]
    float* dws = sq + NBLK;            // [2048 * 8] chunk partials

    region_reduce<<<NBLK, 256, 0, stream>>>(pred, gt, sq, dws);
    finalize<<<1, 256, 0, stream>>>(sq, dws, rgb, th, out);
}